// Round 3
// baseline (5924.500 us; speedup 1.0000x reference)
//
#include <hip/hip_runtime.h>
#include <hip/hip_bf16.h>
#include <cstdint>

// ---------------- degree + rsqrt norm ----------------
__global__ void k_deg(const int* __restrict__ dst, int* __restrict__ deg, int E) {
  int e = blockIdx.x * blockDim.x + threadIdx.x;
  if (e < E) atomicAdd(&deg[dst[e]], 1);
}

__global__ void k_dis(const int* __restrict__ deg, float* __restrict__ dis, int N) {
  int i = blockIdx.x * blockDim.x + threadIdx.x;
  if (i < N) dis[i] = rsqrtf((float)(deg[i] + 1));  // +1 = self loop
}

// ---------------- GEMM: out[N x 128] = A[N x 128] @ W[128 x 128] ----------------
// optional row scale by dis, optional f32 bias, optional dual store
__global__ __launch_bounds__(256) void k_gemm128(
    const float* __restrict__ A, const float* __restrict__ W,
    const float* __restrict__ dis, const float* __restrict__ bias,
    float* __restrict__ out0, float* __restrict__ out1, int N) {
  __shared__ float Ws[128 * 128];  // 64 KB, row-major [k][j]
  __shared__ float As[32 * 128];   // 16 KB, row-major [r][k]
  int tid = threadIdx.x;

  const float4* W4 = (const float4*)W;
  for (int i = tid; i < 4096; i += 256) {
    *(float4*)&Ws[i * 4] = W4[i];
  }

  int row0 = blockIdx.x * 32;
  const float4* A4 = (const float4*)A;  // 32 float4 per row
  for (int i = tid; i < 1024; i += 256) {
    int r = i >> 5, c = i & 31;
    int row = row0 + r;
    float4 v = make_float4(0.f, 0.f, 0.f, 0.f);
    if (row < N) v = A4[(size_t)row * 32 + c];
    *(float4*)&As[r * 128 + c * 4] = v;
  }
  __syncthreads();

  int r0 = (tid >> 5) * 4;   // row group: 8 groups of 4 rows
  int j0 = (tid & 31) * 4;   // col group: 32 groups of 4 cols
  float acc[4][4] = {};
#pragma unroll 4
  for (int k = 0; k < 128; k += 4) {
    float4 a[4], w[4];
#pragma unroll
    for (int rr = 0; rr < 4; ++rr) a[rr] = *(const float4*)&As[(r0 + rr) * 128 + k];
#pragma unroll
    for (int kk = 0; kk < 4; ++kk) w[kk] = *(const float4*)&Ws[(k + kk) * 128 + j0];
#pragma unroll
    for (int rr = 0; rr < 4; ++rr) {
      acc[rr][0] += a[rr].x * w[0].x; acc[rr][1] += a[rr].x * w[0].y;
      acc[rr][2] += a[rr].x * w[0].z; acc[rr][3] += a[rr].x * w[0].w;
      acc[rr][0] += a[rr].y * w[1].x; acc[rr][1] += a[rr].y * w[1].y;
      acc[rr][2] += a[rr].y * w[1].z; acc[rr][3] += a[rr].y * w[1].w;
      acc[rr][0] += a[rr].z * w[2].x; acc[rr][1] += a[rr].z * w[2].y;
      acc[rr][2] += a[rr].z * w[2].z; acc[rr][3] += a[rr].z * w[2].w;
      acc[rr][0] += a[rr].w * w[3].x; acc[rr][1] += a[rr].w * w[3].y;
      acc[rr][2] += a[rr].w * w[3].z; acc[rr][3] += a[rr].w * w[3].w;
    }
  }

  float bj[4] = {0.f, 0.f, 0.f, 0.f};
  if (bias) {
#pragma unroll
    for (int c = 0; c < 4; ++c) bj[c] = bias[j0 + c];
  }
#pragma unroll
  for (int rr = 0; rr < 4; ++rr) {
    int row = row0 + r0 + rr;
    if (row >= N) break;
    float s = dis ? dis[row] : 1.0f;
    float4 o;
    o.x = acc[rr][0] * s + bj[0];
    o.y = acc[rr][1] * s + bj[1];
    o.z = acc[rr][2] * s + bj[2];
    o.w = acc[rr][3] * s + bj[3];
    *(float4*)(out0 + (size_t)row * 128 + j0) = o;
    if (out1) *(float4*)(out1 + (size_t)row * 128 + j0) = o;
  }
}

// ---------------- edge scatter: t[dst] += h[src], 32 lanes x float4 per edge ----------------
__global__ __launch_bounds__(256) void k_scatter(
    const float* __restrict__ h, float* __restrict__ t,
    const int* __restrict__ src, const int* __restrict__ dst, int E) {
  int gid = blockIdx.x * 256 + threadIdx.x;
  int e = gid >> 5, lane = gid & 31;
  if (e >= E) return;
  int s = src[e], d = dst[e];
  float4 v = ((const float4*)(h + (size_t)s * 128))[lane];
  float* p = t + (size_t)d * 128 + lane * 4;
  unsafeAtomicAdd(p + 0, v.x);
  unsafeAtomicAdd(p + 1, v.y);
  unsafeAtomicAdd(p + 2, v.z);
  unsafeAtomicAdd(p + 3, v.w);
}

// ---------------- elementwise: t = relu(dis[row]*t + bias) (in place) ----------------
__global__ void k_finalize(float* __restrict__ t, const float* __restrict__ dis,
                           const float* __restrict__ bias, int N) {
  int i = blockIdx.x * 256 + threadIdx.x;  // float4 index
  if (i >= N * 32) return;
  int row = i >> 5, c4 = (i & 31) * 4;
  float s = dis[row];
  float4 v = ((const float4*)t)[i];
  float4 o;
  o.x = fmaxf(v.x * s + bias[c4 + 0], 0.f);
  o.y = fmaxf(v.y * s + bias[c4 + 1], 0.f);
  o.z = fmaxf(v.z * s + bias[c4 + 2], 0.f);
  o.w = fmaxf(v.w * s + bias[c4 + 3], 0.f);
  ((float4*)t)[i] = o;
}

// ---------------- head: out = log_softmax(A @ Wp2 + bp2), wave per row, f32 out ----------------
__global__ __launch_bounds__(256) void k_head_softmax(
    const float* __restrict__ A, const float* __restrict__ W,
    const float* __restrict__ b, float* __restrict__ out, int N) {
  __shared__ float Ws[128 * 64];      // 32 KB
  __shared__ float rowbuf[4][128];    // 2 KB
  int tid = threadIdx.x;
  const float4* W4 = (const float4*)W;
  for (int i = tid; i < 2048; i += 256) {
    *(float4*)&Ws[i * 4] = W4[i];
  }
  __syncthreads();
  int wave = tid >> 6, lane = tid & 63;
  float bj = b[lane];
  for (int row = blockIdx.x * 4 + wave; row < N; row += gridDim.x * 4) {
    ((float2*)rowbuf[wave])[lane] = ((const float2*)(A + (size_t)row * 128))[lane];
    float acc = bj;
#pragma unroll 8
    for (int k = 0; k < 128; k += 4) {
      float4 r4 = *(const float4*)&rowbuf[wave][k];
      acc += r4.x * Ws[(k + 0) * 64 + lane];
      acc += r4.y * Ws[(k + 1) * 64 + lane];
      acc += r4.z * Ws[(k + 2) * 64 + lane];
      acc += r4.w * Ws[(k + 3) * 64 + lane];
    }
    float m = acc;
#pragma unroll
    for (int off = 32; off > 0; off >>= 1) m = fmaxf(m, __shfl_xor(m, off, 64));
    float ex = expf(acc - m);
    float ssum = ex;
#pragma unroll
    for (int off = 32; off > 0; off >>= 1) ssum += __shfl_xor(ssum, off, 64);
    out[(size_t)row * 64 + lane] = (acc - m) - logf(ssum);
  }
}

extern "C" void kernel_launch(void* const* d_in, const int* in_sizes, int n_in,
                              void* d_out, int out_size, void* d_ws, size_t ws_size,
                              hipStream_t stream) {
  const float* x   = (const float*)d_in[0];
  const int*   ei  = (const int*)d_in[1];
  const float* W1  = (const float*)d_in[2];
  const float* b1  = (const float*)d_in[3];
  const float* W2  = (const float*)d_in[4];
  const float* b2  = (const float*)d_in[5];
  const float* Wp1 = (const float*)d_in[6];
  const float* bp1 = (const float*)d_in[7];
  const float* Wp2 = (const float*)d_in[8];
  const float* bp2 = (const float*)d_in[9];
  float* out = (float*)d_out;

  int N = in_sizes[0] / 128;
  int E = in_sizes[1] / 2;
  const int* src = ei;
  const int* dst = ei + E;

  float* dis  = (float*)d_ws;
  int*   deg  = (int*)(dis + N);
  float* buf0 = (float*)(deg + N);            // 51.2 MB
  float* buf1 = buf0 + (size_t)N * 128;       // 51.2 MB

  hipMemsetAsync(deg, 0, (size_t)N * sizeof(int), stream);
  k_deg<<<(E + 255) / 256, 256, 0, stream>>>(dst, deg, E);
  k_dis<<<(N + 255) / 256, 256, 0, stream>>>(deg, dis, N);

  int gblocks = (N + 31) / 32;
  int eblocks = (int)(((long long)E * 32 + 255) / 256);
  int fblocks = (N * 32 + 255) / 256;

  // layer 1: h1' = dis*(x@W1) -> buf0 and buf1 (self-loop init)
  k_gemm128<<<gblocks, 256, 0, stream>>>(x, W1, dis, nullptr, buf0, buf1, N);
  k_scatter<<<eblocks, 256, 0, stream>>>(buf0, buf1, src, dst, E);
  k_finalize<<<fblocks, 256, 0, stream>>>(buf1, dis, b1, N);  // act1 in buf1

  // layer 2 (in-place dual store is safe: each block reads only rows it writes)
  k_gemm128<<<gblocks, 256, 0, stream>>>(buf1, W2, dis, nullptr, buf0, buf1, N);
  k_scatter<<<eblocks, 256, 0, stream>>>(buf0, buf1, src, dst, E);
  k_finalize<<<fblocks, 256, 0, stream>>>(buf1, dis, b2, N);  // act2 in buf1

  // head MLP: buf0 = act2 @ Wp1 + bp1 (no relu)
  k_gemm128<<<gblocks, 256, 0, stream>>>(buf1, Wp1, nullptr, bp1, buf0, nullptr, N);
  k_head_softmax<<<2048, 256, 0, stream>>>(buf0, Wp2, bp2, out, N);
}

// Round 4
// 891.305 us; speedup vs baseline: 6.6470x; 6.6470x over previous
//
#include <hip/hip_runtime.h>
#include <hip/hip_bf16.h>
#include <cstdint>

// ---------------- degree ----------------
__global__ void k_deg(const int* __restrict__ dst, int* __restrict__ deg, int E) {
  int e = blockIdx.x * blockDim.x + threadIdx.x;
  if (e < E) atomicAdd(&deg[dst[e]], 1);
}

__global__ void k_dis(const int* __restrict__ deg, float* __restrict__ dis, int N) {
  int i = blockIdx.x * blockDim.x + threadIdx.x;
  if (i < N) dis[i] = rsqrtf((float)(deg[i] + 1));  // +1 = self loop
}

// ---------------- segment starts: start[d] = running offset (order-free) ----------------
// wave-level inclusive scan + one atomic per wave on a single global counter.
__global__ void k_start(const int* __restrict__ deg, int* __restrict__ start,
                        int* __restrict__ counter, int N) {
  int i = blockIdx.x * blockDim.x + threadIdx.x;
  int lane = threadIdx.x & 63;
  int v = (i < N) ? deg[i] : 0;
  int incl = v;
#pragma unroll
  for (int off = 1; off < 64; off <<= 1) {
    int t = __shfl_up(incl, off, 64);
    if (lane >= off) incl += t;
  }
  int wtot = __shfl(incl, 63, 64);
  int base = 0;
  if (lane == 0) base = atomicAdd(counter, wtot);
  base = __shfl(base, 0, 64);
  if (i < N) start[i] = base + (incl - v);
}

// ---------------- CSR fill: col[start[d] + cursor[d]++] = src[e] ----------------
__global__ void k_fill(const int* __restrict__ src, const int* __restrict__ dst,
                       const int* __restrict__ start, int* __restrict__ cursor,
                       int* __restrict__ col, int E) {
  int e = blockIdx.x * blockDim.x + threadIdx.x;
  if (e >= E) return;
  int d = dst[e];
  int pos = atomicAdd(&cursor[d], 1);
  col[start[d] + pos] = src[e];
}

// ---------------- GEMM: out[N x 128] = A[N x 128] @ W[128 x 128] ----------------
__global__ __launch_bounds__(256) void k_gemm128(
    const float* __restrict__ A, const float* __restrict__ W,
    const float* __restrict__ dis, const float* __restrict__ bias,
    float* __restrict__ out0, int N) {
  __shared__ float Ws[128 * 128];  // 64 KB, row-major [k][j]
  __shared__ float As[32 * 128];   // 16 KB, row-major [r][k]
  int tid = threadIdx.x;

  const float4* W4 = (const float4*)W;
  for (int i = tid; i < 4096; i += 256) {
    *(float4*)&Ws[i * 4] = W4[i];
  }

  int row0 = blockIdx.x * 32;
  const float4* A4 = (const float4*)A;
  for (int i = tid; i < 1024; i += 256) {
    int r = i >> 5, c = i & 31;
    int row = row0 + r;
    float4 v = make_float4(0.f, 0.f, 0.f, 0.f);
    if (row < N) v = A4[(size_t)row * 32 + c];
    *(float4*)&As[r * 128 + c * 4] = v;
  }
  __syncthreads();

  int r0 = (tid >> 5) * 4;
  int j0 = (tid & 31) * 4;
  float acc[4][4] = {};
#pragma unroll 4
  for (int k = 0; k < 128; k += 4) {
    float4 a[4], w[4];
#pragma unroll
    for (int rr = 0; rr < 4; ++rr) a[rr] = *(const float4*)&As[(r0 + rr) * 128 + k];
#pragma unroll
    for (int kk = 0; kk < 4; ++kk) w[kk] = *(const float4*)&Ws[(k + kk) * 128 + j0];
#pragma unroll
    for (int rr = 0; rr < 4; ++rr) {
      acc[rr][0] += a[rr].x * w[0].x; acc[rr][1] += a[rr].x * w[0].y;
      acc[rr][2] += a[rr].x * w[0].z; acc[rr][3] += a[rr].x * w[0].w;
      acc[rr][0] += a[rr].y * w[1].x; acc[rr][1] += a[rr].y * w[1].y;
      acc[rr][2] += a[rr].y * w[1].z; acc[rr][3] += a[rr].y * w[1].w;
      acc[rr][0] += a[rr].z * w[2].x; acc[rr][1] += a[rr].z * w[2].y;
      acc[rr][2] += a[rr].z * w[2].z; acc[rr][3] += a[rr].z * w[2].w;
      acc[rr][0] += a[rr].w * w[3].x; acc[rr][1] += a[rr].w * w[3].y;
      acc[rr][2] += a[rr].w * w[3].z; acc[rr][3] += a[rr].w * w[3].w;
    }
  }

  float bj[4] = {0.f, 0.f, 0.f, 0.f};
  if (bias) {
#pragma unroll
    for (int c = 0; c < 4; ++c) bj[c] = bias[j0 + c];
  }
#pragma unroll
  for (int rr = 0; rr < 4; ++rr) {
    int row = row0 + r0 + rr;
    if (row >= N) break;
    float s = dis ? dis[row] : 1.0f;
    float4 o;
    o.x = acc[rr][0] * s + bj[0];
    o.y = acc[rr][1] * s + bj[1];
    o.z = acc[rr][2] * s + bj[2];
    o.w = acc[rr][3] * s + bj[3];
    *(float4*)(out0 + (size_t)row * 128 + j0) = o;
  }
}

// ---------------- gather-aggregate + fused finalize ----------------
// half-wave (32 lanes x float4) per node:
// o[d] = relu(dis[d] * (h[d] + sum_{e in seg(d)} h[col[e]]) + bias)
__global__ __launch_bounds__(256) void k_gather(
    const float4* __restrict__ h, float4* __restrict__ o,
    const int* __restrict__ start, const int* __restrict__ deg,
    const int* __restrict__ col, const float* __restrict__ dis,
    const float4* __restrict__ bias4, int N) {
  int tid = threadIdx.x;
  int node = blockIdx.x * 8 + (tid >> 5);
  int lane = tid & 31;
  if (node >= N) return;
  float4 acc = h[(size_t)node * 32 + lane];
  int e = start[node];
  int e_end = e + deg[node];
  for (; e + 1 < e_end; e += 2) {
    int s1 = col[e], s2 = col[e + 1];
    float4 v1 = h[(size_t)s1 * 32 + lane];
    float4 v2 = h[(size_t)s2 * 32 + lane];
    acc.x += v1.x + v2.x; acc.y += v1.y + v2.y;
    acc.z += v1.z + v2.z; acc.w += v1.w + v2.w;
  }
  if (e < e_end) {
    int s1 = col[e];
    float4 v1 = h[(size_t)s1 * 32 + lane];
    acc.x += v1.x; acc.y += v1.y; acc.z += v1.z; acc.w += v1.w;
  }
  float sc = dis[node];
  float4 b = bias4[lane];
  float4 r;
  r.x = fmaxf(acc.x * sc + b.x, 0.f);
  r.y = fmaxf(acc.y * sc + b.y, 0.f);
  r.z = fmaxf(acc.z * sc + b.z, 0.f);
  r.w = fmaxf(acc.w * sc + b.w, 0.f);
  o[(size_t)node * 32 + lane] = r;
}

// ---------------- head: out = log_softmax(A @ Wp2 + bp2), wave per row ----------------
__global__ __launch_bounds__(256) void k_head_softmax(
    const float* __restrict__ A, const float* __restrict__ W,
    const float* __restrict__ b, float* __restrict__ out, int N) {
  __shared__ float Ws[128 * 64];
  __shared__ float rowbuf[4][128];
  int tid = threadIdx.x;
  const float4* W4 = (const float4*)W;
  for (int i = tid; i < 2048; i += 256) {
    *(float4*)&Ws[i * 4] = W4[i];
  }
  __syncthreads();
  int wave = tid >> 6, lane = tid & 63;
  float bj = b[lane];
  for (int row = blockIdx.x * 4 + wave; row < N; row += gridDim.x * 4) {
    ((float2*)rowbuf[wave])[lane] = ((const float2*)(A + (size_t)row * 128))[lane];
    float acc = bj;
#pragma unroll 8
    for (int k = 0; k < 128; k += 4) {
      float4 r4 = *(const float4*)&rowbuf[wave][k];
      acc += r4.x * Ws[(k + 0) * 64 + lane];
      acc += r4.y * Ws[(k + 1) * 64 + lane];
      acc += r4.z * Ws[(k + 2) * 64 + lane];
      acc += r4.w * Ws[(k + 3) * 64 + lane];
    }
    float m = acc;
#pragma unroll
    for (int off = 32; off > 0; off >>= 1) m = fmaxf(m, __shfl_xor(m, off, 64));
    float ex = expf(acc - m);
    float ssum = ex;
#pragma unroll
    for (int off = 32; off > 0; off >>= 1) ssum += __shfl_xor(ssum, off, 64);
    out[(size_t)row * 64 + lane] = (acc - m) - logf(ssum);
  }
}

extern "C" void kernel_launch(void* const* d_in, const int* in_sizes, int n_in,
                              void* d_out, int out_size, void* d_ws, size_t ws_size,
                              hipStream_t stream) {
  const float* x   = (const float*)d_in[0];
  const int*   ei  = (const int*)d_in[1];
  const float* W1  = (const float*)d_in[2];
  const float* b1  = (const float*)d_in[3];
  const float* W2  = (const float*)d_in[4];
  const float* b2  = (const float*)d_in[5];
  const float* Wp1 = (const float*)d_in[6];
  const float* bp1 = (const float*)d_in[7];
  const float* Wp2 = (const float*)d_in[8];
  const float* bp2 = (const float*)d_in[9];
  float* out = (float*)d_out;

  int N = in_sizes[0] / 128;
  int E = in_sizes[1] / 2;
  const int* src = ei;
  const int* dst = ei + E;

  // workspace layout
  float* dis    = (float*)d_ws;             // N f32
  int*   deg    = (int*)(dis + N);          // N i32  } zeroed
  int*   cursor = deg + N;                  // N i32  } zeroed
  int*   counter= cursor + N;               // 16 i32 } zeroed (1 used)
  int*   start  = counter + 16;             // N i32
  int*   col    = start + N;                // E i32
  float* buf0   = (float*)(col + ((E + 3) & ~3));  // N*128 f32
  float* buf1   = buf0 + (size_t)N * 128;          // N*128 f32

  hipMemsetAsync(deg, 0, (size_t)(2 * N + 16) * sizeof(int), stream);

  int eb = (E + 255) / 256;
  int nb = (N + 255) / 256;
  k_deg<<<eb, 256, 0, stream>>>(dst, deg, E);
  k_dis<<<nb, 256, 0, stream>>>(deg, dis, N);
  k_start<<<nb, 256, 0, stream>>>(deg, start, counter, N);
  k_fill<<<eb, 256, 0, stream>>>(src, dst, start, cursor, col, E);

  int gblocks  = (N + 31) / 32;
  int agblocks = (N + 7) / 8;

  // layer 1
  k_gemm128<<<gblocks, 256, 0, stream>>>(x, W1, dis, nullptr, buf0, N);
  k_gather<<<agblocks, 256, 0, stream>>>((const float4*)buf0, (float4*)buf1,
                                         start, deg, col, dis, (const float4*)b1, N);
  // layer 2
  k_gemm128<<<gblocks, 256, 0, stream>>>(buf1, W2, dis, nullptr, buf0, N);
  k_gather<<<agblocks, 256, 0, stream>>>((const float4*)buf0, (float4*)buf1,
                                         start, deg, col, dis, (const float4*)b2, N);
  // head MLP
  k_gemm128<<<gblocks, 256, 0, stream>>>(buf1, Wp1, nullptr, bp1, buf0, N);
  k_head_softmax<<<2048, 256, 0, stream>>>(buf0, Wp2, bp2, out, N);
}

// Round 5
// 609.975 us; speedup vs baseline: 9.7127x; 1.4612x over previous
//
#include <hip/hip_runtime.h>
#include <hip/hip_bf16.h>
#include <cstdint>

typedef __attribute__((ext_vector_type(8))) short short8;     // 8 bf16 frag (4 VGPRs)
typedef __attribute__((ext_vector_type(16))) float f32x16;    // 32x32 accumulator

__device__ __forceinline__ float bflo(uint32_t u) { return __builtin_bit_cast(float, u << 16); }
__device__ __forceinline__ float bfhi(uint32_t u) { return __builtin_bit_cast(float, u & 0xffff0000u); }

__device__ __forceinline__ unsigned short f32_to_bf16_rne(float f) {
  uint32_t u = __builtin_bit_cast(uint32_t, f);
  u += 0x7fffu + ((u >> 16) & 1u);
  return (unsigned short)(u >> 16);
}

// split f32 into truncated-bf16 hi + bf16 lo (residual); hi+lo ~= f to ~2^-16 rel
__device__ __forceinline__ void split2(float f, unsigned short& h, unsigned short& l) {
  uint32_t u = __builtin_bit_cast(uint32_t, f);
  h = (unsigned short)(u >> 16);
  float fh = __builtin_bit_cast(float, u & 0xffff0000u);
  float r = f - fh;  // exact
  l = (unsigned short)(__builtin_bit_cast(uint32_t, r) >> 16);
}

// ---------------- degree ----------------
__global__ void k_deg(const int* __restrict__ dst, int* __restrict__ deg, int E) {
  int e = blockIdx.x * blockDim.x + threadIdx.x;
  if (e < E) atomicAdd(&deg[dst[e]], 1);
}

__global__ void k_dis(const int* __restrict__ deg, float* __restrict__ dis, int N) {
  int i = blockIdx.x * blockDim.x + threadIdx.x;
  if (i < N) dis[i] = rsqrtf((float)(deg[i] + 1));  // +1 = self loop
}

// ---------------- segment starts (order-free): wave scan + one atomic/wave ----------------
__global__ void k_start(const int* __restrict__ deg, int* __restrict__ start,
                        int* __restrict__ counter, int N) {
  int i = blockIdx.x * blockDim.x + threadIdx.x;
  int lane = threadIdx.x & 63;
  int v = (i < N) ? deg[i] : 0;
  int incl = v;
#pragma unroll
  for (int off = 1; off < 64; off <<= 1) {
    int t = __shfl_up(incl, off, 64);
    if (lane >= off) incl += t;
  }
  int wtot = __shfl(incl, 63, 64);
  int base = 0;
  if (lane == 0) base = atomicAdd(counter, wtot);
  base = __shfl(base, 0, 64);
  if (i < N) start[i] = base + (incl - v);
}

// ---------------- CSR fill ----------------
__global__ void k_fill(const int* __restrict__ src, const int* __restrict__ dst,
                       const int* __restrict__ start, int* __restrict__ cursor,
                       int* __restrict__ col, int E) {
  int e = blockIdx.x * blockDim.x + threadIdx.x;
  if (e >= E) return;
  int d = dst[e];
  int pos = atomicAdd(&cursor[d], 1);
  col[start[d] + pos] = src[e];
}

// ---------------- W pre-split: W[k][n] f32 -> Wt_hi[n][k], Wt_lo[n][k] bf16 ----------------
__global__ void k_wsplit(const float* __restrict__ W, unsigned short* __restrict__ Wh,
                         unsigned short* __restrict__ Wl) {
  int idx = blockIdx.x * 256 + threadIdx.x;
  if (idx >= 16384) return;
  int k = idx >> 7, n = idx & 127;
  unsigned short h, l;
  split2(W[idx], h, l);
  Wh[n * 128 + k] = h;
  Wl[n * 128 + k] = l;
}

// ---------------- fold head weights: Wc = Wp1@Wp2 [128x64], bc = bp1@Wp2 + bp2 ----------------
__global__ void k_wcomb(const float* __restrict__ Wp1, const float* __restrict__ Wp2,
                        const float* __restrict__ bp1, const float* __restrict__ bp2,
                        float* __restrict__ Wc, float* __restrict__ bc) {
  if (blockIdx.x < 32) {
    int idx = blockIdx.x * 256 + threadIdx.x;  // 8192 outputs
    int i = idx >> 6, j = idx & 63;
    float acc = 0.f;
    for (int k = 0; k < 128; ++k) acc += Wp1[i * 128 + k] * Wp2[k * 64 + j];
    Wc[idx] = acc;
  } else {
    int j = threadIdx.x;
    if (j < 64) {
      float acc = bp2[j];
      for (int k = 0; k < 128; ++k) acc += bp1[k] * Wp2[k * 64 + j];
      bc[j] = acc;
    }
  }
}

// ---------------- MFMA GEMM: h_bf16[row][128] = rne_bf16(dis[row] * (A @ W)) ----------------
// split-bf16: 3 MFMAs (hh, hl, lh) per K-chunk of 16. Block = 4 waves, tile = 32 rows x 128 cols.
__global__ __launch_bounds__(256) void k_gemm_mfma(
    const float* __restrict__ A, const unsigned short* __restrict__ Wh,
    const unsigned short* __restrict__ Wl, const float* __restrict__ dis,
    unsigned short* __restrict__ out_bf16, int N, int ntiles) {
  __shared__ unsigned short As_hi[32 * 136];  // 136 = pad for conflict-free b128
  __shared__ unsigned short As_lo[32 * 136];
  int tid = threadIdx.x;
  int wave = tid >> 6, lane = tid & 63;
  int n0 = wave * 32;
  int nn = n0 + (lane & 31);
  int khalf = (lane >> 5) * 8;
  int m = lane & 31;

  // B fragments resident in registers (reused across all row tiles)
  short8 bh[8], bl[8];
#pragma unroll
  for (int c = 0; c < 8; ++c) {
    bh[c] = *(const short8*)&Wh[nn * 128 + c * 16 + khalf];
    bl[c] = *(const short8*)&Wl[nn * 128 + c * 16 + khalf];
  }

  for (int t = blockIdx.x; t < ntiles; t += gridDim.x) {
    int row0 = t * 32;
    __syncthreads();  // protect LDS against previous tile's reads
    for (int j = tid; j < 1024; j += 256) {
      int r = j >> 5, c = j & 31;
      int row = row0 + r;
      float4 v = make_float4(0.f, 0.f, 0.f, 0.f);
      if (row < N) v = *(const float4*)&A[(size_t)row * 128 + c * 4];
      unsigned short h0, h1, h2, h3, l0, l1, l2, l3;
      split2(v.x, h0, l0); split2(v.y, h1, l1);
      split2(v.z, h2, l2); split2(v.w, h3, l3);
      ushort4 hv = make_ushort4(h0, h1, h2, h3);
      ushort4 lv = make_ushort4(l0, l1, l2, l3);
      *(ushort4*)&As_hi[r * 136 + c * 4] = hv;
      *(ushort4*)&As_lo[r * 136 + c * 4] = lv;
    }
    __syncthreads();

    f32x16 acc = {};
#pragma unroll
    for (int c = 0; c < 8; ++c) {
      short8 ah = *(const short8*)&As_hi[m * 136 + c * 16 + khalf];
      short8 al = *(const short8*)&As_lo[m * 136 + c * 16 + khalf];
      acc = __builtin_amdgcn_mfma_f32_32x32x16_bf16(ah, bh[c], acc, 0, 0, 0);
      acc = __builtin_amdgcn_mfma_f32_32x32x16_bf16(ah, bl[c], acc, 0, 0, 0);
      acc = __builtin_amdgcn_mfma_f32_32x32x16_bf16(al, bh[c], acc, 0, 0, 0);
    }

    int col = n0 + (lane & 31);
    int rbase = row0 + 4 * (lane >> 5);
#pragma unroll
    for (int reg = 0; reg < 16; ++reg) {
      int row = rbase + (reg & 3) + 8 * (reg >> 2);
      if (row < N) {
        float v = acc[reg] * dis[row];
        out_bf16[(size_t)row * 128 + col] = f32_to_bf16_rne(v);
      }
    }
  }
}

// ---------------- gather-aggregate (bf16 input) + fused finalize ----------------
// o[d] = relu(dis[d] * (h[d] + sum h[col[e]]) + bias), half-wave per node, 4 bf16/lane
__global__ __launch_bounds__(256) void k_gather(
    const unsigned short* __restrict__ h, float4* __restrict__ o,
    const int* __restrict__ start, const int* __restrict__ deg,
    const int* __restrict__ col, const float* __restrict__ dis,
    const float* __restrict__ bias, int N) {
  int tid = threadIdx.x;
  int node = blockIdx.x * 8 + (tid >> 5);
  int lane = tid & 31;
  if (node >= N) return;
  const uint2* h2 = (const uint2*)h;  // 4 bf16 per uint2; row = 32 uint2
  uint2 u = h2[(size_t)node * 32 + lane];
  float ax = bflo(u.x), ay = bfhi(u.x), az = bflo(u.y), aw = bfhi(u.y);
  int e = start[node];
  int e_end = e + deg[node];
  for (; e + 1 < e_end; e += 2) {
    uint2 u1 = h2[(size_t)col[e] * 32 + lane];
    uint2 u2 = h2[(size_t)col[e + 1] * 32 + lane];
    ax += bflo(u1.x) + bflo(u2.x); ay += bfhi(u1.x) + bfhi(u2.x);
    az += bflo(u1.y) + bflo(u2.y); aw += bfhi(u1.y) + bfhi(u2.y);
  }
  if (e < e_end) {
    uint2 u1 = h2[(size_t)col[e] * 32 + lane];
    ax += bflo(u1.x); ay += bfhi(u1.x); az += bflo(u1.y); aw += bfhi(u1.y);
  }
  float sc = dis[node];
  float4 b = ((const float4*)bias)[lane];
  float4 r;
  r.x = fmaxf(ax * sc + b.x, 0.f);
  r.y = fmaxf(ay * sc + b.y, 0.f);
  r.z = fmaxf(az * sc + b.z, 0.f);
  r.w = fmaxf(aw * sc + b.w, 0.f);
  o[(size_t)node * 32 + lane] = r;
}

// ---------------- head: out = log_softmax(A @ Wc + bc), wave per row ----------------
__global__ __launch_bounds__(256) void k_head_softmax(
    const float* __restrict__ A, const float* __restrict__ W,
    const float* __restrict__ b, float* __restrict__ out, int N) {
  __shared__ float Ws[128 * 64];
  __shared__ float rowbuf[4][128];
  int tid = threadIdx.x;
  const float4* W4 = (const float4*)W;
  for (int i = tid; i < 2048; i += 256) {
    *(float4*)&Ws[i * 4] = W4[i];
  }
  __syncthreads();
  int wave = tid >> 6, lane = tid & 63;
  float bj = b[lane];
  for (int row = blockIdx.x * 4 + wave; row < N; row += gridDim.x * 4) {
    ((float2*)rowbuf[wave])[lane] = ((const float2*)(A + (size_t)row * 128))[lane];
    float acc = bj;
#pragma unroll 8
    for (int k = 0; k < 128; k += 4) {
      float4 r4 = *(const float4*)&rowbuf[wave][k];
      acc += r4.x * Ws[(k + 0) * 64 + lane];
      acc += r4.y * Ws[(k + 1) * 64 + lane];
      acc += r4.z * Ws[(k + 2) * 64 + lane];
      acc += r4.w * Ws[(k + 3) * 64 + lane];
    }
    float m = acc;
#pragma unroll
    for (int off = 32; off > 0; off >>= 1) m = fmaxf(m, __shfl_xor(m, off, 64));
    float ex = expf(acc - m);
    float ssum = ex;
#pragma unroll
    for (int off = 32; off > 0; off >>= 1) ssum += __shfl_xor(ssum, off, 64);
    out[(size_t)row * 64 + lane] = (acc - m) - logf(ssum);
  }
}

extern "C" void kernel_launch(void* const* d_in, const int* in_sizes, int n_in,
                              void* d_out, int out_size, void* d_ws, size_t ws_size,
                              hipStream_t stream) {
  const float* x   = (const float*)d_in[0];
  const int*   ei  = (const int*)d_in[1];
  const float* W1  = (const float*)d_in[2];
  const float* b1  = (const float*)d_in[3];
  const float* W2  = (const float*)d_in[4];
  const float* b2  = (const float*)d_in[5];
  const float* Wp1 = (const float*)d_in[6];
  const float* bp1 = (const float*)d_in[7];
  const float* Wp2 = (const float*)d_in[8];
  const float* bp2 = (const float*)d_in[9];
  float* out = (float*)d_out;

  int N = in_sizes[0] / 128;
  int E = in_sizes[1] / 2;
  const int* src = ei;
  const int* dst = ei + E;

  // workspace layout (int granularity)
  float* dis     = (float*)d_ws;                  // N
  int*   deg     = (int*)(dis + N);               // N } zeroed
  int*   cursor  = deg + N;                       // N } zeroed
  int*   counter = cursor + N;                    // 16 } zeroed
  int*   start   = counter + 16;                  // N
  int*   col     = start + N;                     // E
  int*   p       = col + ((E + 3) & ~3);
  unsigned short* Wt1h = (unsigned short*)p;      // 16384 us = 8192 int
  unsigned short* Wt1l = Wt1h + 16384;
  unsigned short* Wt2h = Wt1l + 16384;
  unsigned short* Wt2l = Wt2h + 16384;
  float* Wc   = (float*)(Wt2l + 16384);           // 8192 f32
  float* bc   = Wc + 8192;                        // 64 f32 (+pad)
  unsigned short* hbuf = (unsigned short*)(bc + 80);  // N*128 bf16 = 25.6 MB
  float* act  = (float*)(hbuf + (size_t)N * 128); // N*128 f32 = 51.2 MB

  hipMemsetAsync(deg, 0, (size_t)(2 * N + 16) * sizeof(int), stream);

  int eb = (E + 255) / 256;
  int nb = (N + 255) / 256;
  k_deg<<<eb, 256, 0, stream>>>(dst, deg, E);
  k_dis<<<nb, 256, 0, stream>>>(deg, dis, N);
  k_start<<<nb, 256, 0, stream>>>(deg, start, counter, N);
  k_fill<<<eb, 256, 0, stream>>>(src, dst, start, cursor, col, E);
  k_wsplit<<<64, 256, 0, stream>>>(W1, Wt1h, Wt1l);
  k_wsplit<<<64, 256, 0, stream>>>(W2, Wt2h, Wt2l);
  k_wcomb<<<33, 256, 0, stream>>>(Wp1, Wp2, bp1, bp2, Wc, bc);

  int ntiles = (N + 31) / 32;
  int gemm_grid = ntiles < 1024 ? ntiles : 1024;
  int agblocks = (N + 7) / 8;

  // layer 1
  k_gemm_mfma<<<gemm_grid, 256, 0, stream>>>(x, Wt1h, Wt1l, dis, hbuf, N, ntiles);
  k_gather<<<agblocks, 256, 0, stream>>>(hbuf, (float4*)act, start, deg, col, dis, b1, N);
  // layer 2
  k_gemm_mfma<<<gemm_grid, 256, 0, stream>>>(act, Wt2h, Wt2l, dis, hbuf, N, ntiles);
  k_gather<<<agblocks, 256, 0, stream>>>(hbuf, (float4*)act, start, deg, col, dis, b2, N);
  // folded head
  k_head_softmax<<<2048, 256, 0, stream>>>(act, Wc, bc, out, N);
}

// Round 6
// 536.087 us; speedup vs baseline: 11.0514x; 1.1378x over previous
//
#include <hip/hip_runtime.h>
#include <hip/hip_bf16.h>
#include <cstdint>

typedef __attribute__((ext_vector_type(8))) short short8;     // 8 bf16 frag (4 VGPRs)
typedef __attribute__((ext_vector_type(16))) float f32x16;    // 32x32 accumulator

__device__ __forceinline__ float bflo(uint32_t u) { return __builtin_bit_cast(float, u << 16); }
__device__ __forceinline__ float bfhi(uint32_t u) { return __builtin_bit_cast(float, u & 0xffff0000u); }

__device__ __forceinline__ unsigned short f32_to_bf16_rne(float f) {
  uint32_t u = __builtin_bit_cast(uint32_t, f);
  u += 0x7fffu + ((u >> 16) & 1u);
  return (unsigned short)(u >> 16);
}

// split f32 into truncated-bf16 hi + bf16 lo (residual); hi+lo ~= f to ~2^-16 rel
__device__ __forceinline__ void split2(float f, unsigned short& h, unsigned short& l) {
  uint32_t u = __builtin_bit_cast(uint32_t, f);
  h = (unsigned short)(u >> 16);
  float fh = __builtin_bit_cast(float, u & 0xffff0000u);
  float r = f - fh;  // exact
  l = (unsigned short)(__builtin_bit_cast(uint32_t, r) >> 16);
}

// ---------------- degree ----------------
__global__ void k_deg(const int* __restrict__ dst, int* __restrict__ deg, int E) {
  int e = blockIdx.x * blockDim.x + threadIdx.x;
  if (e < E) atomicAdd(&deg[dst[e]], 1);
}

__global__ void k_dis(const int* __restrict__ deg, float* __restrict__ dis, int N) {
  int i = blockIdx.x * blockDim.x + threadIdx.x;
  if (i < N) dis[i] = rsqrtf((float)(deg[i] + 1));  // +1 = self loop
}

// ---------------- segment starts (order-free): wave scan + one atomic/wave ----------------
__global__ void k_start(const int* __restrict__ deg, int* __restrict__ start,
                        int* __restrict__ counter, int N) {
  int i = blockIdx.x * blockDim.x + threadIdx.x;
  int lane = threadIdx.x & 63;
  int v = (i < N) ? deg[i] : 0;
  int incl = v;
#pragma unroll
  for (int off = 1; off < 64; off <<= 1) {
    int t = __shfl_up(incl, off, 64);
    if (lane >= off) incl += t;
  }
  int wtot = __shfl(incl, 63, 64);
  int base = 0;
  if (lane == 0) base = atomicAdd(counter, wtot);
  base = __shfl(base, 0, 64);
  if (i < N) start[i] = base + (incl - v);
}

// ---------------- CSR fill ----------------
__global__ void k_fill(const int* __restrict__ src, const int* __restrict__ dst,
                       const int* __restrict__ start, int* __restrict__ cursor,
                       int* __restrict__ col, int E) {
  int e = blockIdx.x * blockDim.x + threadIdx.x;
  if (e >= E) return;
  int d = dst[e];
  int pos = atomicAdd(&cursor[d], 1);
  col[start[d] + pos] = src[e];
}

// ---------------- W pre-split: W[k][n] f32 -> Wt_hi[n][k], Wt_lo[n][k] bf16 ----------------
__global__ void k_wsplit(const float* __restrict__ W, unsigned short* __restrict__ Wh,
                         unsigned short* __restrict__ Wl) {
  int idx = blockIdx.x * 256 + threadIdx.x;
  if (idx >= 16384) return;
  int k = idx >> 7, n = idx & 127;
  unsigned short h, l;
  split2(W[idx], h, l);
  Wh[n * 128 + k] = h;
  Wl[n * 128 + k] = l;
}

// ------- fold head: Wc = Wp1@Wp2 [128x64] -> split+transposed bf16; bc = bp1@Wp2 + bp2 -------
__global__ void k_wcomb(const float* __restrict__ Wp1, const float* __restrict__ Wp2,
                        const float* __restrict__ bp1, const float* __restrict__ bp2,
                        unsigned short* __restrict__ Wch, unsigned short* __restrict__ Wcl,
                        float* __restrict__ bc) {
  if (blockIdx.x < 32) {
    int idx = blockIdx.x * 256 + threadIdx.x;  // 8192 outputs
    int k = idx >> 6, j = idx & 63;
    float acc = 0.f;
    for (int t = 0; t < 128; ++t) acc += Wp1[k * 128 + t] * Wp2[t * 64 + j];
    unsigned short h, l;
    split2(acc, h, l);
    Wch[j * 128 + k] = h;
    Wcl[j * 128 + k] = l;
  } else {
    int j = threadIdx.x;
    if (j < 64) {
      float acc = bp2[j];
      for (int t = 0; t < 128; ++t) acc += bp1[t] * Wp2[t * 64 + j];
      bc[j] = acc;
    }
  }
}

// ---------------- MFMA GEMM: hbuf[row][128] = rne_bf16(dis[row] * (A @ W)) ----------------
// AF32: A is f32, split to hi/lo, 3 MFMAs/chunk.  !AF32: A is bf16, 2 MFMAs/chunk.
template <bool AF32>
__global__ __launch_bounds__(256) void k_gemm_mfma(
    const void* __restrict__ Av, const unsigned short* __restrict__ Wh,
    const unsigned short* __restrict__ Wl, const float* __restrict__ dis,
    unsigned short* __restrict__ out_bf16, int N, int ntiles) {
  __shared__ unsigned short As_hi[32 * 136];  // 136 = pad for conflict-free b128
  __shared__ unsigned short As_lo[32 * 136];  // unused in bf16 path
  int tid = threadIdx.x;
  int wave = tid >> 6, lane = tid & 63;
  int n0 = wave * 32;
  int nn = n0 + (lane & 31);
  int khalf = (lane >> 5) * 8;
  int m = lane & 31;

  // B fragments resident in registers (reused across all row tiles)
  short8 bh[8], bl[8];
#pragma unroll
  for (int c = 0; c < 8; ++c) {
    bh[c] = *(const short8*)&Wh[nn * 128 + c * 16 + khalf];
    bl[c] = *(const short8*)&Wl[nn * 128 + c * 16 + khalf];
  }

  for (int t = blockIdx.x; t < ntiles; t += gridDim.x) {
    int row0 = t * 32;
    __syncthreads();  // protect LDS against previous tile's reads
    if (AF32) {
      const float* A = (const float*)Av;
      for (int j = tid; j < 1024; j += 256) {
        int r = j >> 5, c = j & 31;
        int row = row0 + r;
        float4 v = make_float4(0.f, 0.f, 0.f, 0.f);
        if (row < N) v = *(const float4*)&A[(size_t)row * 128 + c * 4];
        unsigned short h0, h1, h2, h3, l0, l1, l2, l3;
        split2(v.x, h0, l0); split2(v.y, h1, l1);
        split2(v.z, h2, l2); split2(v.w, h3, l3);
        *(ushort4*)&As_hi[r * 136 + c * 4] = make_ushort4(h0, h1, h2, h3);
        *(ushort4*)&As_lo[r * 136 + c * 4] = make_ushort4(l0, l1, l2, l3);
      }
    } else {
      const unsigned short* A = (const unsigned short*)Av;
      for (int j = tid; j < 512; j += 256) {
        int r = j >> 4, c = j & 15;
        int row = row0 + r;
        uint4 v = make_uint4(0u, 0u, 0u, 0u);
        if (row < N) v = *(const uint4*)&A[(size_t)row * 128 + c * 8];
        *(uint4*)&As_hi[r * 136 + c * 8] = v;
      }
    }
    __syncthreads();

    f32x16 acc = {};
#pragma unroll
    for (int c = 0; c < 8; ++c) {
      short8 ah = *(const short8*)&As_hi[m * 136 + c * 16 + khalf];
      acc = __builtin_amdgcn_mfma_f32_32x32x16_bf16(ah, bh[c], acc, 0, 0, 0);
      acc = __builtin_amdgcn_mfma_f32_32x32x16_bf16(ah, bl[c], acc, 0, 0, 0);
      if (AF32) {
        short8 al = *(const short8*)&As_lo[m * 136 + c * 16 + khalf];
        acc = __builtin_amdgcn_mfma_f32_32x32x16_bf16(al, bh[c], acc, 0, 0, 0);
      }
    }

    int col = n0 + (lane & 31);
    int rbase = row0 + 4 * (lane >> 5);
#pragma unroll
    for (int reg = 0; reg < 16; ++reg) {
      int row = rbase + (reg & 3) + 8 * (reg >> 2);
      if (row < N) {
        float v = acc[reg] * dis[row];
        out_bf16[(size_t)row * 128 + col] = f32_to_bf16_rne(v);
      }
    }
  }
}

// ---------------- gather-aggregate (bf16 in) + fused finalize -> bf16 out ----------------
// o[d] = rne_bf16(relu(dis[d] * (h[d] + sum h[col[e]]) + bias)), half-wave per node
__global__ __launch_bounds__(256) void k_gather(
    const unsigned short* __restrict__ h, unsigned short* __restrict__ o,
    const int* __restrict__ start, const int* __restrict__ deg,
    const int* __restrict__ col, const float* __restrict__ dis,
    const float* __restrict__ bias, int N) {
  int tid = threadIdx.x;
  int node = blockIdx.x * 8 + (tid >> 5);
  int lane = tid & 31;
  if (node >= N) return;
  const uint2* h2 = (const uint2*)h;  // 4 bf16 per uint2; row = 32 uint2
  uint2 u = h2[(size_t)node * 32 + lane];
  float ax = bflo(u.x), ay = bfhi(u.x), az = bflo(u.y), aw = bfhi(u.y);
  int e = start[node];
  int e_end = e + deg[node];
  for (; e + 1 < e_end; e += 2) {
    uint2 u1 = h2[(size_t)col[e] * 32 + lane];
    uint2 u2 = h2[(size_t)col[e + 1] * 32 + lane];
    ax += bflo(u1.x) + bflo(u2.x); ay += bfhi(u1.x) + bfhi(u2.x);
    az += bflo(u1.y) + bflo(u2.y); aw += bfhi(u1.y) + bfhi(u2.y);
  }
  if (e < e_end) {
    uint2 u1 = h2[(size_t)col[e] * 32 + lane];
    ax += bflo(u1.x); ay += bfhi(u1.x); az += bflo(u1.y); aw += bfhi(u1.y);
  }
  float sc = dis[node];
  float4 b = ((const float4*)bias)[lane];
  float rx = fmaxf(ax * sc + b.x, 0.f);
  float ry = fmaxf(ay * sc + b.y, 0.f);
  float rz = fmaxf(az * sc + b.z, 0.f);
  float rw = fmaxf(aw * sc + b.w, 0.f);
  uint2 po;
  po.x = ((uint32_t)f32_to_bf16_rne(ry) << 16) | f32_to_bf16_rne(rx);
  po.y = ((uint32_t)f32_to_bf16_rne(rw) << 16) | f32_to_bf16_rne(rz);
  ((uint2*)o)[(size_t)node * 32 + lane] = po;
}

// ---------------- head: out = log_softmax(act @ Wc + bc) via MFMA, fused softmax ----------------
// block = 4 waves = 64 rows; wave (rt,ct): rows rt*32.., cols ct*32..
__global__ __launch_bounds__(256) void k_head_mfma(
    const unsigned short* __restrict__ act, const unsigned short* __restrict__ Wch,
    const unsigned short* __restrict__ Wcl, const float* __restrict__ bc,
    float* __restrict__ out, int N) {
  __shared__ unsigned short As[64 * 136];  // 17.4 KB
  __shared__ float red[2][2][64];          // [max/sum][ct][row_local]
  int tid = threadIdx.x;
  int wave = tid >> 6, lane = tid & 63;
  int rt = wave >> 1, ct = wave & 1;
  int colj = ct * 32 + (lane & 31);
  int khalf = (lane >> 5) * 8;
  int m = lane & 31;

  short8 bh[8], bl[8];
#pragma unroll
  for (int c = 0; c < 8; ++c) {
    bh[c] = *(const short8*)&Wch[colj * 128 + c * 16 + khalf];
    bl[c] = *(const short8*)&Wcl[colj * 128 + c * 16 + khalf];
  }

  int row0 = blockIdx.x * 64;
  for (int j = tid; j < 1024; j += 256) {
    int r = j >> 4, c = j & 15;
    int row = row0 + r;
    uint4 v = make_uint4(0u, 0u, 0u, 0u);
    if (row < N) v = *(const uint4*)&act[(size_t)row * 128 + c * 8];
    *(uint4*)&As[r * 136 + c * 8] = v;
  }
  __syncthreads();

  f32x16 acc = {};
  int mrow = rt * 32 + m;
#pragma unroll
  for (int c = 0; c < 8; ++c) {
    short8 ah = *(const short8*)&As[mrow * 136 + c * 16 + khalf];
    acc = __builtin_amdgcn_mfma_f32_32x32x16_bf16(ah, bh[c], acc, 0, 0, 0);
    acc = __builtin_amdgcn_mfma_f32_32x32x16_bf16(ah, bl[c], acc, 0, 0, 0);
  }

  float bcv = bc[colj];
  float lg[16], mx[16];
#pragma unroll
  for (int reg = 0; reg < 16; ++reg) {
    lg[reg] = acc[reg] + bcv;
    float v = lg[reg];
#pragma unroll
    for (int off = 16; off > 0; off >>= 1) v = fmaxf(v, __shfl_xor(v, off, 32));
    mx[reg] = v;  // tile row-max, present in all 32 lanes of the half-group
  }
  if ((lane & 31) == 0) {
#pragma unroll
    for (int reg = 0; reg < 16; ++reg) {
      int rl = rt * 32 + (reg & 3) + 8 * (reg >> 2) + 4 * (lane >> 5);
      red[0][ct][rl] = mx[reg];
    }
  }
  __syncthreads();

  float ex[16], sm[16];
#pragma unroll
  for (int reg = 0; reg < 16; ++reg) {
    int rl = rt * 32 + (reg & 3) + 8 * (reg >> 2) + 4 * (lane >> 5);
    float rmax = fmaxf(red[0][0][rl], red[0][1][rl]);
    ex[reg] = lg[reg] - rmax;
    float v = expf(ex[reg]);
#pragma unroll
    for (int off = 16; off > 0; off >>= 1) v += __shfl_xor(v, off, 32);
    sm[reg] = v;
  }
  if ((lane & 31) == 0) {
#pragma unroll
    for (int reg = 0; reg < 16; ++reg) {
      int rl = rt * 32 + (reg & 3) + 8 * (reg >> 2) + 4 * (lane >> 5);
      red[1][ct][rl] = sm[reg];
    }
  }
  __syncthreads();

#pragma unroll
  for (int reg = 0; reg < 16; ++reg) {
    int rl = rt * 32 + (reg & 3) + 8 * (reg >> 2) + 4 * (lane >> 5);
    int row = row0 + rl;
    if (row < N) {
      float total = red[1][0][rl] + red[1][1][rl];
      out[(size_t)row * 64 + colj] = ex[reg] - logf(total);
    }
  }
}

extern "C" void kernel_launch(void* const* d_in, const int* in_sizes, int n_in,
                              void* d_out, int out_size, void* d_ws, size_t ws_size,
                              hipStream_t stream) {
  const float* x   = (const float*)d_in[0];
  const int*   ei  = (const int*)d_in[1];
  const float* W1  = (const float*)d_in[2];
  const float* b1  = (const float*)d_in[3];
  const float* W2  = (const float*)d_in[4];
  const float* b2  = (const float*)d_in[5];
  const float* Wp1 = (const float*)d_in[6];
  const float* bp1 = (const float*)d_in[7];
  const float* Wp2 = (const float*)d_in[8];
  const float* bp2 = (const float*)d_in[9];
  float* out = (float*)d_out;

  int N = in_sizes[0] / 128;
  int E = in_sizes[1] / 2;
  const int* src = ei;
  const int* dst = ei + E;

  // workspace layout (int granularity)
  float* dis     = (float*)d_ws;                  // N
  int*   deg     = (int*)(dis + N);               // N } zeroed
  int*   cursor  = deg + N;                       // N } zeroed
  int*   counter = cursor + N;                    // 16 } zeroed
  int*   start   = counter + 16;                  // N
  int*   col     = start + N;                     // E
  int*   p       = col + ((E + 3) & ~3);
  unsigned short* Wt1h = (unsigned short*)p;      // 16384 each
  unsigned short* Wt1l = Wt1h + 16384;
  unsigned short* Wt2h = Wt1l + 16384;
  unsigned short* Wt2l = Wt2h + 16384;
  unsigned short* Wch  = Wt2l + 16384;            // 8192
  unsigned short* Wcl  = Wch + 8192;              // 8192
  float* bc   = (float*)(Wcl + 8192);             // 64 f32 (+pad)
  unsigned short* hbuf = (unsigned short*)(bc + 80);   // N*128 bf16 = 25.6 MB
  unsigned short* act  = hbuf + (size_t)N * 128;       // N*128 bf16 = 25.6 MB

  hipMemsetAsync(deg, 0, (size_t)(2 * N + 16) * sizeof(int), stream);

  int eb = (E + 255) / 256;
  int nb = (N + 255) / 256;
  k_deg<<<eb, 256, 0, stream>>>(dst, deg, E);
  k_dis<<<nb, 256, 0, stream>>>(deg, dis, N);
  k_start<<<nb, 256, 0, stream>>>(deg, start, counter, N);
  k_fill<<<eb, 256, 0, stream>>>(src, dst, start, cursor, col, E);
  k_wsplit<<<64, 256, 0, stream>>>(W1, Wt1h, Wt1l);
  k_wsplit<<<64, 256, 0, stream>>>(W2, Wt2h, Wt2l);
  k_wcomb<<<33, 256, 0, stream>>>(Wp1, Wp2, bp1, bp2, Wch, Wcl, bc);

  int ntiles = (N + 31) / 32;
  int gemm_grid = ntiles < 1024 ? ntiles : 1024;
  int agblocks = (N + 7) / 8;
  int hblocks = (N + 63) / 64;

  // layer 1
  k_gemm_mfma<true><<<gemm_grid, 256, 0, stream>>>(x, Wt1h, Wt1l, dis, hbuf, N, ntiles);
  k_gather<<<agblocks, 256, 0, stream>>>(hbuf, act, start, deg, col, dis, b1, N);
  // layer 2
  k_gemm_mfma<false><<<gemm_grid, 256, 0, stream>>>(act, Wt2h, Wt2l, dis, hbuf, N, ntiles);
  k_gather<<<agblocks, 256, 0, stream>>>(hbuf, act, start, deg, col, dis, b2, N);
  // folded head (MFMA + fused log_softmax)
  k_head_mfma<<<hblocks, 256, 0, stream>>>(act, Wch, Wcl, bc, out, N);
}

// Round 7
// 409.322 us; speedup vs baseline: 14.4739x; 1.3097x over previous
//
#include <hip/hip_runtime.h>
#include <hip/hip_bf16.h>
#include <cstdint>

typedef __attribute__((ext_vector_type(8))) short short8;     // 8 bf16 frag (4 VGPRs)
typedef __attribute__((ext_vector_type(16))) float f32x16;    // 32x32 accumulator
typedef unsigned short us;

#define BIN_SHIFT 9
#define BIN_NODES 512
#define CAPB 12288   // per-bin capacity (mean 8163, +45 sigma)
#define EPB 4096     // edges per binA block

__device__ __forceinline__ float bflo(uint32_t u) { return __builtin_bit_cast(float, u << 16); }
__device__ __forceinline__ float bfhi(uint32_t u) { return __builtin_bit_cast(float, u & 0xffff0000u); }

__device__ __forceinline__ us f32_to_bf16_rne(float f) {
  uint32_t u = __builtin_bit_cast(uint32_t, f);
  u += 0x7fffu + ((u >> 16) & 1u);
  return (us)(u >> 16);
}

// split f32 into truncated-bf16 hi + bf16 lo (residual); hi+lo ~= f to ~2^-16 rel
__device__ __forceinline__ void split2(float f, us& h, us& l) {
  uint32_t u = __builtin_bit_cast(uint32_t, f);
  h = (us)(u >> 16);
  float fh = __builtin_bit_cast(float, u & 0xffff0000u);
  float r = f - fh;  // exact
  l = (us)(__builtin_bit_cast(uint32_t, r) >> 16);
}

// ---------------- pass A: bin (dst,src) pairs by dst>>9 with dense batched appends ----------------
__global__ __launch_bounds__(256) void k_binA(
    const int* __restrict__ src, const int* __restrict__ dst,
    uint2* __restrict__ binbuf, int* __restrict__ gcur, int E, int nbins) {
  __shared__ uint2 stage[EPB];                       // 32 KB
  __shared__ int cnt[256], base[256], cur[256], gbase[256];
  int tid = threadIdx.x;
  int e0 = blockIdx.x * EPB;
  int ne = min(EPB, E - e0);
  if (ne <= 0) return;
  cnt[tid] = 0;
  __syncthreads();
  for (int i = tid; i < ne; i += 256) atomicAdd(&cnt[dst[e0 + i] >> BIN_SHIFT], 1);
  __syncthreads();
  // exclusive scan cnt[256] -> base (wave 0, 4 chunks of 64)
  if (tid < 64) {
    int carry = 0;
#pragma unroll
    for (int c = 0; c < 4; ++c) {
      int v = cnt[c * 64 + tid];
      int incl = v;
#pragma unroll
      for (int off = 1; off < 64; off <<= 1) {
        int t = __shfl_up(incl, off, 64);
        if (tid >= off) incl += t;
      }
      base[c * 64 + tid] = carry + incl - v;
      carry += __shfl(incl, 63, 64);
    }
  }
  __syncthreads();
  if (tid < nbins && cnt[tid] > 0) gbase[tid] = atomicAdd(&gcur[tid], cnt[tid]);
  cur[tid] = base[tid];
  __syncthreads();
  for (int i = tid; i < ne; i += 256) {
    int d = dst[e0 + i], s = src[e0 + i];
    int p = atomicAdd(&cur[d >> BIN_SHIFT], 1);
    stage[p] = make_uint2((unsigned)d, (unsigned)s);
  }
  __syncthreads();
  for (int i = tid; i < ne; i += 256) {
    uint2 en = stage[i];
    int b = en.x >> BIN_SHIFT;
    int gi = gbase[b] + (i - base[b]);
    if (gi < CAPB) binbuf[(size_t)b * CAPB + gi] = en;
  }
}

// ---------------- pass B: per-bin deg/dis/start + col fill, all dense writes ----------------
__global__ __launch_bounds__(256) void k_passB(
    const uint2* __restrict__ binbuf, const int* __restrict__ gcur,
    int* __restrict__ deg, float* __restrict__ dis, int* __restrict__ start,
    int* __restrict__ col, int N, int nbins) {
  __shared__ int hist[512], lstart[512], cur[512];
  __shared__ int colstage[CAPB];                     // 48 KB
  __shared__ int binbase_s;
  int b = blockIdx.x, tid = threadIdx.x;
  int node0 = b << BIN_SHIFT;
  int cnt = min(gcur[b], CAPB);
  hist[tid] = 0; hist[tid + 256] = 0;
  __syncthreads();
  const uint2* bp = binbuf + (size_t)b * CAPB;
  for (int i = tid; i < cnt; i += 256) atomicAdd(&hist[bp[i].x & (BIN_NODES - 1)], 1);
  __syncthreads();
  if (tid < 64) {
    // binbase = sum of capped counts of previous bins
    int s = 0;
    for (int i = tid; i < b; i += 64) s += min(gcur[i], CAPB);
#pragma unroll
    for (int off = 32; off; off >>= 1) s += __shfl_xor(s, off, 64);
    if (tid == 0) binbase_s = s;
    // exclusive scan hist[512] -> lstart (8 chunks of 64)
    int carry = 0;
#pragma unroll
    for (int c = 0; c < 8; ++c) {
      int v = hist[c * 64 + tid];
      int incl = v;
#pragma unroll
      for (int off = 1; off < 64; off <<= 1) {
        int t = __shfl_up(incl, off, 64);
        if (tid >= off) incl += t;
      }
      lstart[c * 64 + tid] = carry + incl - v;
      carry += __shfl(incl, 63, 64);
    }
  }
  __syncthreads();
  int binbase = binbase_s;
  for (int i = tid; i < 512; i += 256) {
    int node = node0 + i;
    if (node < N) {
      int dg = hist[i];
      deg[node] = dg;
      dis[node] = rsqrtf((float)(dg + 1));
      start[node] = binbase + lstart[i];
    }
  }
  cur[tid] = lstart[tid]; cur[tid + 256] = lstart[tid + 256];
  __syncthreads();
  for (int i = tid; i < cnt; i += 256) {
    uint2 en = bp[i];
    int p = atomicAdd(&cur[en.x & (BIN_NODES - 1)], 1);
    colstage[p] = (int)en.y;
  }
  __syncthreads();
  for (int i = tid; i < cnt; i += 256) col[binbase + i] = colstage[i];
}

// ---------------- merged weight prep: split W1,W2; fold+split head ----------------
__global__ void k_prep(const float* __restrict__ W1, const float* __restrict__ W2,
                       const float* __restrict__ Wp1, const float* __restrict__ Wp2,
                       const float* __restrict__ bp1, const float* __restrict__ bp2,
                       us* __restrict__ Wt1h, us* __restrict__ Wt1l,
                       us* __restrict__ Wt2h, us* __restrict__ Wt2l,
                       us* __restrict__ Wch, us* __restrict__ Wcl, float* __restrict__ bc) {
  int blk = blockIdx.x, tid = threadIdx.x;
  if (blk < 128) {
    const float* W = (blk < 64) ? W1 : W2;
    us* Wh = (blk < 64) ? Wt1h : Wt2h;
    us* Wl = (blk < 64) ? Wt1l : Wt2l;
    int idx = (blk & 63) * 256 + tid;   // 16384
    int k = idx >> 7, n = idx & 127;
    us h, l;
    split2(W[idx], h, l);
    Wh[n * 128 + k] = h;
    Wl[n * 128 + k] = l;
  } else if (blk < 160) {
    int idx = (blk - 128) * 256 + tid;  // 8192
    int k = idx >> 6, j = idx & 63;
    float acc = 0.f;
    for (int t = 0; t < 128; ++t) acc += Wp1[k * 128 + t] * Wp2[t * 64 + j];
    us h, l;
    split2(acc, h, l);
    Wch[j * 128 + k] = h;
    Wcl[j * 128 + k] = l;
  } else {
    int j = tid;
    if (j < 64) {
      float acc = bp2[j];
      for (int t = 0; t < 128; ++t) acc += bp1[t] * Wp2[t * 64 + j];
      bc[j] = acc;
    }
  }
}

// ---------------- MFMA GEMM: hbuf[row][128] = rne_bf16(dis[row] * (A @ W)) ----------------
template <bool AF32>
__global__ __launch_bounds__(256) void k_gemm_mfma(
    const void* __restrict__ Av, const us* __restrict__ Wh,
    const us* __restrict__ Wl, const float* __restrict__ dis,
    us* __restrict__ out_bf16, int N, int ntiles) {
  __shared__ us As_hi[32 * 136];
  __shared__ us As_lo[32 * 136];
  int tid = threadIdx.x;
  int wave = tid >> 6, lane = tid & 63;
  int n0 = wave * 32;
  int nn = n0 + (lane & 31);
  int khalf = (lane >> 5) * 8;
  int m = lane & 31;

  short8 bh[8], bl[8];
#pragma unroll
  for (int c = 0; c < 8; ++c) {
    bh[c] = *(const short8*)&Wh[nn * 128 + c * 16 + khalf];
    bl[c] = *(const short8*)&Wl[nn * 128 + c * 16 + khalf];
  }

  for (int t = blockIdx.x; t < ntiles; t += gridDim.x) {
    int row0 = t * 32;
    __syncthreads();
    if (AF32) {
      const float* A = (const float*)Av;
      for (int j = tid; j < 1024; j += 256) {
        int r = j >> 5, c = j & 31;
        int row = row0 + r;
        float4 v = make_float4(0.f, 0.f, 0.f, 0.f);
        if (row < N) v = *(const float4*)&A[(size_t)row * 128 + c * 4];
        us h0, h1, h2, h3, l0, l1, l2, l3;
        split2(v.x, h0, l0); split2(v.y, h1, l1);
        split2(v.z, h2, l2); split2(v.w, h3, l3);
        *(ushort4*)&As_hi[r * 136 + c * 4] = make_ushort4(h0, h1, h2, h3);
        *(ushort4*)&As_lo[r * 136 + c * 4] = make_ushort4(l0, l1, l2, l3);
      }
    } else {
      const us* A = (const us*)Av;
      for (int j = tid; j < 512; j += 256) {
        int r = j >> 4, c = j & 15;
        int row = row0 + r;
        uint4 v = make_uint4(0u, 0u, 0u, 0u);
        if (row < N) v = *(const uint4*)&A[(size_t)row * 128 + c * 8];
        *(uint4*)&As_hi[r * 136 + c * 8] = v;
      }
    }
    __syncthreads();

    f32x16 acc = {};
#pragma unroll
    for (int c = 0; c < 8; ++c) {
      short8 ah = *(const short8*)&As_hi[m * 136 + c * 16 + khalf];
      acc = __builtin_amdgcn_mfma_f32_32x32x16_bf16(ah, bh[c], acc, 0, 0, 0);
      acc = __builtin_amdgcn_mfma_f32_32x32x16_bf16(ah, bl[c], acc, 0, 0, 0);
      if (AF32) {
        short8 al = *(const short8*)&As_lo[m * 136 + c * 16 + khalf];
        acc = __builtin_amdgcn_mfma_f32_32x32x16_bf16(al, bh[c], acc, 0, 0, 0);
      }
    }

    int col = n0 + (lane & 31);
    int rbase = row0 + 4 * (lane >> 5);
#pragma unroll
    for (int reg = 0; reg < 16; ++reg) {
      int row = rbase + (reg & 3) + 8 * (reg >> 2);
      if (row < N) {
        float v = acc[reg] * dis[row];
        out_bf16[(size_t)row * 128 + col] = f32_to_bf16_rne(v);
      }
    }
  }
}

// ---------------- gather-aggregate (bf16 in) + fused finalize -> bf16 out ----------------
__global__ __launch_bounds__(256) void k_gather(
    const us* __restrict__ h, us* __restrict__ o,
    const int* __restrict__ start, const int* __restrict__ deg,
    const int* __restrict__ col, const float* __restrict__ dis,
    const float* __restrict__ bias, int N) {
  int tid = threadIdx.x;
  int node = blockIdx.x * 8 + (tid >> 5);
  int lane = tid & 31;
  if (node >= N) return;
  const uint2* h2 = (const uint2*)h;
  uint2 u = h2[(size_t)node * 32 + lane];
  float ax = bflo(u.x), ay = bfhi(u.x), az = bflo(u.y), aw = bfhi(u.y);
  int e = start[node];
  int e_end = e + deg[node];
  for (; e + 1 < e_end; e += 2) {
    uint2 u1 = h2[(size_t)col[e] * 32 + lane];
    uint2 u2 = h2[(size_t)col[e + 1] * 32 + lane];
    ax += bflo(u1.x) + bflo(u2.x); ay += bfhi(u1.x) + bfhi(u2.x);
    az += bflo(u1.y) + bflo(u2.y); aw += bfhi(u1.y) + bfhi(u2.y);
  }
  if (e < e_end) {
    uint2 u1 = h2[(size_t)col[e] * 32 + lane];
    ax += bflo(u1.x); ay += bfhi(u1.x); az += bflo(u1.y); aw += bfhi(u1.y);
  }
  float sc = dis[node];
  float4 b = ((const float4*)bias)[lane];
  float rx = fmaxf(ax * sc + b.x, 0.f);
  float ry = fmaxf(ay * sc + b.y, 0.f);
  float rz = fmaxf(az * sc + b.z, 0.f);
  float rw = fmaxf(aw * sc + b.w, 0.f);
  uint2 po;
  po.x = ((uint32_t)f32_to_bf16_rne(ry) << 16) | f32_to_bf16_rne(rx);
  po.y = ((uint32_t)f32_to_bf16_rne(rw) << 16) | f32_to_bf16_rne(rz);
  ((uint2*)o)[(size_t)node * 32 + lane] = po;
}

// ---------------- head: out = log_softmax(act @ Wc + bc) via MFMA, fused softmax ----------------
__global__ __launch_bounds__(256) void k_head_mfma(
    const us* __restrict__ act, const us* __restrict__ Wch,
    const us* __restrict__ Wcl, const float* __restrict__ bc,
    float* __restrict__ out, int N) {
  __shared__ us As[64 * 136];
  __shared__ float red[2][2][64];
  int tid = threadIdx.x;
  int wave = tid >> 6, lane = tid & 63;
  int rt = wave >> 1, ct = wave & 1;
  int colj = ct * 32 + (lane & 31);
  int khalf = (lane >> 5) * 8;
  int m = lane & 31;

  short8 bh[8], bl[8];
#pragma unroll
  for (int c = 0; c < 8; ++c) {
    bh[c] = *(const short8*)&Wch[colj * 128 + c * 16 + khalf];
    bl[c] = *(const short8*)&Wcl[colj * 128 + c * 16 + khalf];
  }

  int row0 = blockIdx.x * 64;
  for (int j = tid; j < 1024; j += 256) {
    int r = j >> 4, c = j & 15;
    int row = row0 + r;
    uint4 v = make_uint4(0u, 0u, 0u, 0u);
    if (row < N) v = *(const uint4*)&act[(size_t)row * 128 + c * 8];
    *(uint4*)&As[r * 136 + c * 8] = v;
  }
  __syncthreads();

  f32x16 acc = {};
  int mrow = rt * 32 + m;
#pragma unroll
  for (int c = 0; c < 8; ++c) {
    short8 ah = *(const short8*)&As[mrow * 136 + c * 16 + khalf];
    acc = __builtin_amdgcn_mfma_f32_32x32x16_bf16(ah, bh[c], acc, 0, 0, 0);
    acc = __builtin_amdgcn_mfma_f32_32x32x16_bf16(ah, bl[c], acc, 0, 0, 0);
  }

  float bcv = bc[colj];
  float lg[16], mx[16];
#pragma unroll
  for (int reg = 0; reg < 16; ++reg) {
    lg[reg] = acc[reg] + bcv;
    float v = lg[reg];
#pragma unroll
    for (int off = 16; off > 0; off >>= 1) v = fmaxf(v, __shfl_xor(v, off, 32));
    mx[reg] = v;
  }
  if ((lane & 31) == 0) {
#pragma unroll
    for (int reg = 0; reg < 16; ++reg) {
      int rl = rt * 32 + (reg & 3) + 8 * (reg >> 2) + 4 * (lane >> 5);
      red[0][ct][rl] = mx[reg];
    }
  }
  __syncthreads();

  float ex[16], sm[16];
#pragma unroll
  for (int reg = 0; reg < 16; ++reg) {
    int rl = rt * 32 + (reg & 3) + 8 * (reg >> 2) + 4 * (lane >> 5);
    float rmax = fmaxf(red[0][0][rl], red[0][1][rl]);
    ex[reg] = lg[reg] - rmax;
    float v = expf(ex[reg]);
#pragma unroll
    for (int off = 16; off > 0; off >>= 1) v += __shfl_xor(v, off, 32);
    sm[reg] = v;
  }
  if ((lane & 31) == 0) {
#pragma unroll
    for (int reg = 0; reg < 16; ++reg) {
      int rl = rt * 32 + (reg & 3) + 8 * (reg >> 2) + 4 * (lane >> 5);
      red[1][ct][rl] = sm[reg];
    }
  }
  __syncthreads();

#pragma unroll
  for (int reg = 0; reg < 16; ++reg) {
    int rl = rt * 32 + (reg & 3) + 8 * (reg >> 2) + 4 * (lane >> 5);
    int row = row0 + rl;
    if (row < N) {
      float total = red[1][0][rl] + red[1][1][rl];
      out[(size_t)row * 64 + colj] = ex[reg] - logf(total);
    }
  }
}

extern "C" void kernel_launch(void* const* d_in, const int* in_sizes, int n_in,
                              void* d_out, int out_size, void* d_ws, size_t ws_size,
                              hipStream_t stream) {
  const float* x   = (const float*)d_in[0];
  const int*   ei  = (const int*)d_in[1];
  const float* W1  = (const float*)d_in[2];
  const float* b1  = (const float*)d_in[3];
  const float* W2  = (const float*)d_in[4];
  const float* b2  = (const float*)d_in[5];
  const float* Wp1 = (const float*)d_in[6];
  const float* bp1 = (const float*)d_in[7];
  const float* Wp2 = (const float*)d_in[8];
  const float* bp2 = (const float*)d_in[9];
  float* out = (float*)d_out;

  int N = in_sizes[0] / 128;
  int E = in_sizes[1] / 2;
  const int* src = ei;
  const int* dst = ei + E;
  int nbins = (N + BIN_NODES - 1) >> BIN_SHIFT;

  // workspace layout (int granularity)
  float* dis   = (float*)d_ws;                    // N
  int*   deg   = (int*)(dis + N);                 // N
  int*   start = deg + N;                         // N
  int*   col   = start + N;                       // E
  int*   gcur  = col + ((E + 3) & ~3);            // 256 (zeroed)
  us* Wt1h = (us*)(gcur + 256);                   // 16384 each
  us* Wt1l = Wt1h + 16384;
  us* Wt2h = Wt1l + 16384;
  us* Wt2l = Wt2h + 16384;
  us* Wch  = Wt2l + 16384;                        // 8192
  us* Wcl  = Wch + 8192;                          // 8192
  float* bc = (float*)(Wcl + 8192);               // 64 (+pad)
  uint2* binbuf = (uint2*)(bc + 80);              // nbins*CAPB uint2 (~19.3 MB)
  us* hbuf = (us*)(binbuf + (size_t)nbins * CAPB);  // N*128 bf16 = 25.6 MB
  us* act  = hbuf + (size_t)N * 128;                // N*128 bf16 = 25.6 MB

  hipMemsetAsync(gcur, 0, 256 * sizeof(int), stream);

  int ablocks = (E + EPB - 1) / EPB;
  k_binA<<<ablocks, 256, 0, stream>>>(src, dst, binbuf, gcur, E, nbins);
  k_passB<<<nbins, 256, 0, stream>>>(binbuf, gcur, deg, dis, start, col, N, nbins);
  k_prep<<<161, 256, 0, stream>>>(W1, W2, Wp1, Wp2, bp1, bp2,
                                  Wt1h, Wt1l, Wt2h, Wt2l, Wch, Wcl, bc);

  int ntiles = (N + 31) / 32;
  int gemm_grid = ntiles < 1024 ? ntiles : 1024;
  int agblocks = (N + 7) / 8;
  int hblocks = (N + 63) / 64;

  // layer 1
  k_gemm_mfma<true><<<gemm_grid, 256, 0, stream>>>(x, Wt1h, Wt1l, dis, hbuf, N, ntiles);
  k_gather<<<agblocks, 256, 0, stream>>>(hbuf, act, start, deg, col, dis, b1, N);
  // layer 2
  k_gemm_mfma<false><<<gemm_grid, 256, 0, stream>>>(act, Wt2h, Wt2l, dis, hbuf, N, ntiles);
  k_gather<<<agblocks, 256, 0, stream>>>(hbuf, act, start, deg, col, dis, b2, N);
  // folded head (MFMA + fused log_softmax)
  k_head_mfma<<<hblocks, 256, 0, stream>>>(act, Wch, Wcl, bc, out, N);
}